// Round 3
// baseline (216.925 us; speedup 1.0000x reference)
//
#include <hip/hip_runtime.h>

// BaconAdditionReasoner: y[b,k] = norm_k( 1 - prod_{i+j==k} (1 - clamp(min(p1p_i, p2p_j))) )
// where p1p = p1 @ minmax_norm(W1), p2p = p2 @ minmax_norm(W2).
//
// R2 algebra (kept): 1 - min(ap_i,bp_j) = max(1-ap_i, 1-bp_j); A_i = 1 - a@W1n
// folded into the matmul; clamps dropped (s in [0,1], error << threshold).
// R4 (kept): wn in LDS broadcast; prep fused (t<20 of every block).
//
// R7: amortize + pack. Evidence: R1-R6 (six structures: fetch-path variants,
// coalesced LDS staging, SGPR weights, persistent pipeline w/ reg prefetch)
// ALL flat at 47-52us; occupancy halved with zero effect; no pipe >31%.
// => not latency, not occupancy, not fetch pattern. Per-row issue accounting:
// ~460 VALU + 60 LDS weight-reads + ~25 mem ops = ~560 instrs/row ~= 25-35
// cyc/row/CU issue cost vs 50 measured -> issue-rate floor with overlap slop.
// Fix the two biggest terms:
//  (a) weight ds_reads are row-invariant -> ROWS=4 rows/thread, one k-loop
//      reads weights ONCE for 4 rows: 60 -> 15 reads/row.
//  (b) matmul as packed fp32: float2 accumulators + __builtin_elementwise_fma
//      -> v_pk_fma_f32, 400 -> 200 fma instrs per 4 rows.
// prod/max phase (200/row) is irreducible scalar (no v_pk_max_f32 on CDNA4).
// VGPR ~190 -> 2 waves/SIMD; R6 proved occupancy isn't binding.

typedef float v2f __attribute__((ext_vector_type(2)));

#define NBLOCKS 1024
#define ROWS 4            // NBLOCKS * 256 * ROWS = 1048576 = B

__global__ __launch_bounds__(256, 2) void bacon_main(
    const float* __restrict__ p1, const float* __restrict__ p2,
    const float* __restrict__ W1, const float* __restrict__ W2,
    float* __restrict__ out)
{
    __shared__ __align__(16) float s_out[2][4864];   // double-buffered store stage
    __shared__ __align__(16) float s_w[240];         // wn: [2][10][12] stride-12 padded

    const int t = threadIdx.x;
    const int blk = blockIdx.x;
    const size_t base = (size_t)blk * (256 * ROWS);

    // ---- issue all 4 rows' input loads up front (no deps, max overlap) ----
    float2 va[ROWS][5], vb[ROWS][5];
    #pragma unroll
    for (int r = 0; r < ROWS; ++r) {
        const float2* g1 = (const float2*)(p1 + (base + (size_t)r * 256 + t) * 10);
        const float2* g2 = (const float2*)(p2 + (base + (size_t)r * 256 + t) * 10);
        #pragma unroll
        for (int e = 0; e < 5; ++e) { va[r][e] = g1[e]; vb[r][e] = g2[e]; }
    }

    // ---- fused prep: threads 0..19 minmax-normalize one W row into LDS ----
    if (t < 20) {
        const float* row = ((t < 10) ? W1 : W2) + (t % 10) * 10;
        float r[10];
        #pragma unroll
        for (int i = 0; i < 10; ++i) r[i] = row[i];
        float lo = r[0], hi = r[0];
        #pragma unroll
        for (int i = 1; i < 10; ++i) {
            lo = fminf(lo, r[i]);
            hi = fmaxf(hi, r[i]);
        }
        float inv = 1.0f / (hi - lo + 1e-8f);
        float* o = s_w + ((t < 10) ? 0 : 120) + (t % 10) * 12;
        #pragma unroll
        for (int i = 0; i < 10; ++i) o[i] = (r[i] - lo) * inv;
        o[10] = 0.0f; o[11] = 0.0f;
    }
    __syncthreads();

    // ---- shared k-loop: weights read ONCE, applied to 4 rows; pk_fma math ----
    v2f A2[ROWS][5], B2[ROWS][5];
    #pragma unroll
    for (int r = 0; r < ROWS; ++r)
        #pragma unroll
        for (int m = 0; m < 5; ++m) { A2[r][m] = (v2f){1.0f, 1.0f}; B2[r][m] = (v2f){1.0f, 1.0f}; }

    #pragma unroll
    for (int k = 0; k < 10; ++k) {
        const float4* w1q = (const float4*)(s_w + k * 12);          // 48B-aligned
        const float4* w2q = (const float4*)(s_w + 120 + k * 12);
        float4 u0 = w1q[0], u1 = w1q[1];
        float2 u2 = *(const float2*)(s_w + k * 12 + 8);
        float4 v0 = w2q[0], v1 = w2q[1];
        float2 v2 = *(const float2*)(s_w + 120 + k * 12 + 8);
        v2f uw[5] = { {u0.x, u0.y}, {u0.z, u0.w}, {u1.x, u1.y}, {u1.z, u1.w}, {u2.x, u2.y} };
        v2f vw[5] = { {v0.x, v0.y}, {v0.z, v0.w}, {v1.x, v1.y}, {v1.z, v1.w}, {v2.x, v2.y} };
        #pragma unroll
        for (int r = 0; r < ROWS; ++r) {
            const float ak = (k & 1) ? va[r][k >> 1].y : va[r][k >> 1].x;
            const float bk = (k & 1) ? vb[r][k >> 1].y : vb[r][k >> 1].x;
            const v2f na = (v2f){-ak, -ak};
            const v2f nb = (v2f){-bk, -bk};
            #pragma unroll
            for (int m = 0; m < 5; ++m) {
                A2[r][m] = __builtin_elementwise_fma(na, uw[m], A2[r][m]);  // v_pk_fma_f32
                B2[r][m] = __builtin_elementwise_fma(nb, vw[m], B2[r][m]);
            }
        }
    }

    // ---- per-row epilogue: 100-pair product, normalize, staged store ----
    #pragma unroll
    for (int r = 0; r < ROWS; ++r) {
        float A[10], Bv[10];
        #pragma unroll
        for (int m = 0; m < 5; ++m) {
            A[2 * m] = A2[r][m].x;  A[2 * m + 1] = A2[r][m].y;
            Bv[2 * m] = B2[r][m].x; Bv[2 * m + 1] = B2[r][m].y;
        }

        float prod[19];
        #pragma unroll
        for (int k = 0; k < 19; ++k) prod[k] = 1.0f;
        #pragma unroll
        for (int i = 0; i < 10; ++i) {
            #pragma unroll
            for (int j = 0; j < 10; ++j) {
                prod[i + j] *= fmaxf(A[i], Bv[j]);
            }
        }

        float y[19];
        float tot = 0.0f;
        #pragma unroll
        for (int k = 0; k < 19; ++k) { y[k] = 1.0f - prod[k]; tot += y[k]; }
        float invn = __builtin_amdgcn_rcpf(tot + 1e-9f);

        // double-buffered staging: iter r reads buf(r&1) before barrier r+1;
        // iter r+2 rewrites buf(r&1) only after barrier r+1 -> safe, 1 barrier/row.
        const int cur = r & 1;
        #pragma unroll
        for (int k = 0; k < 19; ++k) s_out[cur][t * 19 + k] = y[k] * invn;
        __syncthreads();

        {
            const float4* so = (const float4*)s_out[cur];               // 1216 float4
            float4* go = (float4*)(out + ((size_t)blk * ROWS + r) * 4864);
            #pragma unroll
            for (int it = 0; it < 5; ++it) {
                int idx = t + it * 256;
                if (idx < 1216) go[idx] = so[idx];   // 1216 = 19*64: wave-uniform
            }
        }
    }
}

extern "C" void kernel_launch(void* const* d_in, const int* in_sizes, int n_in,
                              void* d_out, int out_size, void* d_ws, size_t ws_size,
                              hipStream_t stream) {
    const float* p1 = (const float*)d_in[0];
    const float* p2 = (const float*)d_in[1];
    const float* W1 = (const float*)d_in[2];
    const float* W2 = (const float*)d_in[3];
    // d_in[4] = mask: bins are i+j, computed directly — mask unused.
    bacon_main<<<NBLOCKS, 256, 0, stream>>>(p1, p2, W1, W2, (float*)d_out);
}

// Round 5
// 152.437 us; speedup vs baseline: 1.4230x; 1.4230x over previous
//
#include <hip/hip_runtime.h>

// BaconAdditionReasoner: y[b,k] = norm_k( 1 - prod_{i+j==k} (1 - clamp(min(p1p_i, p2p_j))) )
// where p1p = p1 @ minmax_norm(W1), p2p = p2 @ minmax_norm(W2).
//
// R2 algebra (kept): 1 - min(ap_i,bp_j) = max(1-ap_i, 1-bp_j); A_i = 1 - a@W1n
// folded into the matmul; clamps dropped (s in [0,1], error << threshold).
// R4 (kept): wn in LDS broadcast; prep fused (t<20 of every block).
//
// R8 = R7 minus the spills. R7 (ROWS=4, launch_bounds(256,2)) spilled ~120
// dwords/thread to scratch: FETCH +114MB, WRITE +129MB, VALUBusy 7%, 114us.
// The amortization idea was never tested. Fix: ROWS=2 (working set ~150 VGPR,
// fits the 256 arch-VGPR cap), NO min-occupancy clause (R6 proved occupancy
// non-binding -> give the allocator the whole file). Kept from R7: weights
// read once per k for both rows (60 -> 30 ds_reads/row), v_pk_fma_f32 matmul
// (400 -> 200 fma instrs per 2 rows). Added: nontemporal output stores (pure
// streaming, keep out of L2). Tripwire: WRITE_SIZE must be exactly 77824 KB
// and FETCH ~41 MB; any excess = spills again.
//
// R9: R8 verbatim, fixing the compile error — __builtin_nontemporal_store
// requires a native clang vector type, not HIP_vector_type float4. The
// store path now uses ext_vector_type(4) (v4f) for staging reads + stores.

typedef float v2f __attribute__((ext_vector_type(2)));
typedef float v4f __attribute__((ext_vector_type(4)));

#define NBLOCKS 2048
#define ROWS 2            // NBLOCKS * 256 * ROWS = 1048576 = B

__global__ __launch_bounds__(256) void bacon_main(
    const float* __restrict__ p1, const float* __restrict__ p2,
    const float* __restrict__ W1, const float* __restrict__ W2,
    float* __restrict__ out)
{
    __shared__ __align__(16) float s_out[ROWS][4864];  // one buffer per row set
    __shared__ __align__(16) float s_w[240];           // wn: [2][10][12] stride-12 padded

    const int t = threadIdx.x;
    const int blk = blockIdx.x;
    const size_t base = (size_t)blk * (256 * ROWS);

    // ---- issue both rows' input loads up front (no deps, max overlap) ----
    float2 va[ROWS][5], vb[ROWS][5];
    #pragma unroll
    for (int r = 0; r < ROWS; ++r) {
        const float2* g1 = (const float2*)(p1 + (base + (size_t)r * 256 + t) * 10);
        const float2* g2 = (const float2*)(p2 + (base + (size_t)r * 256 + t) * 10);
        #pragma unroll
        for (int e = 0; e < 5; ++e) { va[r][e] = g1[e]; vb[r][e] = g2[e]; }
    }

    // ---- fused prep: threads 0..19 minmax-normalize one W row into LDS ----
    if (t < 20) {
        const float* row = ((t < 10) ? W1 : W2) + (t % 10) * 10;
        float r[10];
        #pragma unroll
        for (int i = 0; i < 10; ++i) r[i] = row[i];
        float lo = r[0], hi = r[0];
        #pragma unroll
        for (int i = 1; i < 10; ++i) {
            lo = fminf(lo, r[i]);
            hi = fmaxf(hi, r[i]);
        }
        float inv = 1.0f / (hi - lo + 1e-8f);
        float* o = s_w + ((t < 10) ? 0 : 120) + (t % 10) * 12;
        #pragma unroll
        for (int i = 0; i < 10; ++i) o[i] = (r[i] - lo) * inv;
        o[10] = 0.0f; o[11] = 0.0f;
    }
    __syncthreads();

    // ---- unpack rows to scalars (register renaming only) ----
    float a[ROWS][10], b[ROWS][10];
    #pragma unroll
    for (int r = 0; r < ROWS; ++r)
        #pragma unroll
        for (int e = 0; e < 5; ++e) {
            a[r][2 * e] = va[r][e].x; a[r][2 * e + 1] = va[r][e].y;
            b[r][2 * e] = vb[r][e].x; b[r][2 * e + 1] = vb[r][e].y;
        }

    // ---- shared k-loop: weights read ONCE per k for both rows; pk_fma ----
    v2f A2[ROWS][5], B2[ROWS][5];
    #pragma unroll
    for (int r = 0; r < ROWS; ++r)
        #pragma unroll
        for (int m = 0; m < 5; ++m) { A2[r][m] = (v2f){1.0f, 1.0f}; B2[r][m] = (v2f){1.0f, 1.0f}; }

    #pragma unroll
    for (int k = 0; k < 10; ++k) {
        const float4* w1q = (const float4*)(s_w + k * 12);          // 48B-aligned
        const float4* w2q = (const float4*)(s_w + 120 + k * 12);
        float4 u0 = w1q[0], u1 = w1q[1];
        float2 u2 = *(const float2*)(s_w + k * 12 + 8);
        float4 v0 = w2q[0], v1 = w2q[1];
        float2 v2 = *(const float2*)(s_w + 120 + k * 12 + 8);
        v2f uw[5] = { {u0.x, u0.y}, {u0.z, u0.w}, {u1.x, u1.y}, {u1.z, u1.w}, {u2.x, u2.y} };
        v2f vw[5] = { {v0.x, v0.y}, {v0.z, v0.w}, {v1.x, v1.y}, {v1.z, v1.w}, {v2.x, v2.y} };
        #pragma unroll
        for (int r = 0; r < ROWS; ++r) {
            const v2f na = (v2f){-a[r][k], -a[r][k]};
            const v2f nb = (v2f){-b[r][k], -b[r][k]};
            #pragma unroll
            for (int m = 0; m < 5; ++m) {
                A2[r][m] = __builtin_elementwise_fma(na, uw[m], A2[r][m]);  // v_pk_fma_f32
                B2[r][m] = __builtin_elementwise_fma(nb, vw[m], B2[r][m]);
            }
        }
    }

    // ---- per-row epilogue: 100-pair product, normalize, staged store ----
    #pragma unroll
    for (int r = 0; r < ROWS; ++r) {
        float A[10], Bv[10];
        #pragma unroll
        for (int m = 0; m < 5; ++m) {
            A[2 * m] = A2[r][m].x;  A[2 * m + 1] = A2[r][m].y;
            Bv[2 * m] = B2[r][m].x; Bv[2 * m + 1] = B2[r][m].y;
        }

        float prod[19];
        #pragma unroll
        for (int k = 0; k < 19; ++k) prod[k] = 1.0f;
        #pragma unroll
        for (int i = 0; i < 10; ++i) {
            #pragma unroll
            for (int j = 0; j < 10; ++j) {
                prod[i + j] *= fmaxf(A[i], Bv[j]);
            }
        }

        float y[19];
        float tot = 0.0f;
        #pragma unroll
        for (int k = 0; k < 19; ++k) { y[k] = 1.0f - prod[k]; tot += y[k]; }
        float invn = __builtin_amdgcn_rcpf(tot + 1e-9f);

        // distinct buffer per r -> r=1's writes never race r=0's post-barrier reads
        #pragma unroll
        for (int k = 0; k < 19; ++k) s_out[r][t * 19 + k] = y[k] * invn;
        __syncthreads();

        {
            const v4f* so = (const v4f*)s_out[r];                       // 1216 vec4
            v4f* go = (v4f*)(out + ((size_t)blk * ROWS + r) * 4864);
            #pragma unroll
            for (int it = 0; it < 5; ++it) {
                int idx = t + it * 256;
                if (idx < 1216)                       // 1216 = 19*64: wave-uniform
                    __builtin_nontemporal_store(so[idx], go + idx);
            }
        }
    }
}

extern "C" void kernel_launch(void* const* d_in, const int* in_sizes, int n_in,
                              void* d_out, int out_size, void* d_ws, size_t ws_size,
                              hipStream_t stream) {
    const float* p1 = (const float*)d_in[0];
    const float* p2 = (const float*)d_in[1];
    const float* W1 = (const float*)d_in[2];
    const float* W2 = (const float*)d_in[3];
    // d_in[4] = mask: bins are i+j, computed directly — mask unused.
    bacon_main<<<NBLOCKS, 256, 0, stream>>>(p1, p2, W1, W2, (float*)d_out);
}